// Round 4
// baseline (584.265 us; speedup 1.0000x reference)
//
#include <hip/hip_runtime.h>

// GCN 2-layer + linear head on MI355X — bucketed-sort aggregation, no global atomics.
// out = relu(agg(relu(agg(X)@W1 + b1)@W2) + b2) @ Wl + bl
// agg(Y) = D^-1/2 (A+I) D^-1/2 Y  (commutes with dense transform; layer 1 aggregates
// X at 26 feats, layer 2 transforms first at 32 feats).
//
// Pipeline: coarse per-(block,bucket) LDS histogram -> 2-level scan -> atomic-free
// scatter of packed {src,dstlow} words (edges sorted by 128-node bucket) ->
// per-bucket LDS degree count (dis) -> per-bucket edge-parallel LDS f32 accumulation.

#define TPB 256
#define ATB 512              // threads for agg kernels (16 subwaves of 32)
#define NPB 128              // nodes per bucket  (dstlow = 7 bits)
#define EPB 8192             // edges per hist/scatter block
#define NBUCK_MAX 1024

// ---- CSR-ish build ---------------------------------------------------------

__global__ __launch_bounds__(TPB) void coarse_hist_kernel(
        const int* __restrict__ dst, int* __restrict__ H, int e, int nbuck, int eb) {
    __shared__ int lh[NBUCK_MAX];
    int t = threadIdx.x;
    for (int b = t; b < nbuck; b += TPB) lh[b] = 0;
    __syncthreads();
    int j0 = blockIdx.x * EPB;
    int j1 = min(e, j0 + EPB);
    for (int j = j0 + t; j < j1; j += TPB)
        atomicAdd(&lh[dst[j] >> 7], 1);
    __syncthreads();
    for (int b = t; b < nbuck; b += TPB)
        H[b * eb + blockIdx.x] = lh[b];
}

__global__ __launch_bounds__(TPB) void scan_block_kernel(
        const int* __restrict__ in, int* __restrict__ outx, int* __restrict__ bsum, int m) {
    __shared__ int s[TPB];
    int i = blockIdx.x * TPB + threadIdx.x;
    int v = (i < m) ? in[i] : 0;
    s[threadIdx.x] = v;
    __syncthreads();
#pragma unroll
    for (int d = 1; d < TPB; d <<= 1) {
        int t = (threadIdx.x >= d) ? s[threadIdx.x - d] : 0;
        __syncthreads();
        s[threadIdx.x] += t;
        __syncthreads();
    }
    if (i < m) outx[i] = s[threadIdx.x] - v;  // exclusive
    if (threadIdx.x == TPB - 1) bsum[blockIdx.x] = s[TPB - 1];
}

__global__ __launch_bounds__(512) void scan_bsum_kernel(int* bsum, int nb) {  // nb <= 512
    __shared__ int s[512];
    int i = threadIdx.x;
    int v = (i < nb) ? bsum[i] : 0;
    s[i] = v;
    __syncthreads();
#pragma unroll
    for (int d = 1; d < 512; d <<= 1) {
        int t = (i >= d) ? s[i - d] : 0;
        __syncthreads();
        s[i] += t;
        __syncthreads();
    }
    if (i < nb) bsum[i] = s[i] - v;
}

__global__ __launch_bounds__(TPB) void add_offs_kernel(
        int* __restrict__ SH, const int* __restrict__ bsum, int m) {
    int i = blockIdx.x * TPB + threadIdx.x;
    if (i < m) SH[i] += bsum[i >> 8];
}

// scatter edges into bucket-sorted order; packed word = (src<<7) | (dst & 127)
__global__ __launch_bounds__(TPB) void bucket_scatter_kernel(
        const int* __restrict__ src, const int* __restrict__ dst,
        const int* __restrict__ SH, int* __restrict__ sorted, int e, int nbuck, int eb) {
    __shared__ int lc[NBUCK_MAX];
    int t = threadIdx.x;
    for (int b = t; b < nbuck; b += TPB) lc[b] = SH[b * eb + blockIdx.x];
    __syncthreads();
    int j0 = blockIdx.x * EPB;
    int j1 = min(e, j0 + EPB);
    for (int j = j0 + t; j < j1; j += TPB) {
        int d = dst[j];
        int s = src[j];
        int pos = atomicAdd(&lc[d >> 7], 1);      // LDS atomic only
        sorted[pos] = (s << 7) | (d & 127);
    }
}

// per-bucket in-degree via LDS counters -> dis = rsqrt(deg+1)
__global__ __launch_bounds__(NPB) void bucket_dis_kernel(
        const int* __restrict__ sorted, const int* __restrict__ SH,
        float* __restrict__ dis, int e, int n, int nbuck, int eb) {
    __shared__ int lc[NPB];
    int b = blockIdx.x;
    int t = threadIdx.x;
    lc[t] = 0;
    __syncthreads();
    int start = SH[b * eb];
    int end = (b + 1 < nbuck) ? SH[(b + 1) * eb] : e;
    for (int j = start + t; j < end; j += NPB)
        atomicAdd(&lc[sorted[j] & 127], 1);
    __syncthreads();
    int node = b * NPB + t;
    if (node < n) dis[node] = rsqrtf((float)lc[t] + 1.0f);
}

// ---- layer 1 aggregation: sum1[g][f] = dis[g]*x[g][f] + sum dis[s]*x[s][f] --

__global__ __launch_bounds__(ATB) void agg1_kernel(
        const float* __restrict__ x, const float* __restrict__ dis,
        const int* __restrict__ sorted, const int* __restrict__ SH,
        float* __restrict__ sum1, int e, int n, int nbuck, int eb) {
    __shared__ float acc[NPB][27];                // 13.5 KB, stride 27 kills conflicts
    int t = threadIdx.x;
    for (int i = t; i < NPB * 27; i += ATB) ((float*)acc)[i] = 0.0f;
    __syncthreads();
    int b = blockIdx.x;
    int start = SH[b * eb];
    int end = (b + 1 < nbuck) ? SH[(b + 1) * eb] : e;
    int sw = t >> 5, f = t & 31;                  // 16 subwaves of 32 lanes
    for (int j = start + sw; j < end; j += 16) {
        int w = sorted[j];                        // broadcast load
        int s = w >> 7;
        int dl = w & 127;
        if (f < 26) {
            float v = dis[s] * x[(size_t)s * 26 + f];
            atomicAdd(&acc[dl][f], v);            // ds_add_f32
        }
    }
    __syncthreads();
    int base = b * NPB;
    for (int i = t; i < NPB * 26; i += ATB) {
        int nl = i / 26, f2 = i - nl * 26;
        int g = base + nl;
        if (g < n)
            sum1[(size_t)g * 26 + f2] = acc[nl][f2] + dis[g] * x[(size_t)g * 26 + f2];
    }
}

// h1 = relu(dis[g]*sum1[g] @ W1 + b1),  16 nodes/block
__global__ __launch_bounds__(TPB) void gemm1_kernel(
        const float* __restrict__ sum1, const float* __restrict__ dis,
        const float* __restrict__ W, const float* __restrict__ b1,
        float* __restrict__ h1, int n) {
    __shared__ float sW[26 * 64];
    __shared__ float sx[16][27];
    int t = threadIdx.x;
    for (int i = t; i < 26 * 64; i += TPB) sW[i] = W[i];
    int node0 = blockIdx.x * 16;
    for (int i = t; i < 16 * 26; i += TPB) {
        int r = i / 26, c = i - r * 26;
        int g = node0 + r;
        sx[r][c] = (g < n) ? dis[g] * sum1[(size_t)g * 26 + c] : 0.0f;
    }
    __syncthreads();
    int f = t & 63;
    int rr = t >> 6;  // 0..3
    float bias = b1[f];
#pragma unroll
    for (int p = 0; p < 4; ++p) {
        int r = rr * 4 + p;   // rows 0..15
        int g = node0 + r;
        if (g < n) {
            float a = bias;
#pragma unroll
            for (int k = 0; k < 26; ++k) a += sx[r][k] * sW[k * 64 + f];
            h1[(size_t)g * 64 + f] = fmaxf(a, 0.0f);
        }
    }
}

// xw2s = dis[g] * (h1[g] @ W2),  16 nodes/block (pre-scaled for aggregation)
__global__ __launch_bounds__(TPB) void gemm2_kernel(
        const float* __restrict__ h1, const float* __restrict__ dis,
        const float* __restrict__ W, float* __restrict__ xw2s, int n) {
    __shared__ float sW[64 * 32];
    __shared__ float sh[16][65];
    int t = threadIdx.x;
    for (int i = t; i < 64 * 32; i += TPB) sW[i] = W[i];
    int node0 = blockIdx.x * 16;
    for (int i = t; i < 16 * 64; i += TPB) {
        int r = i >> 6, c = i & 63;
        int g = node0 + r;
        sh[r][c] = (g < n) ? h1[(size_t)g * 64 + c] : 0.0f;
    }
    __syncthreads();
    int f = t & 31;
    int rr = t >> 5;  // 0..7
#pragma unroll
    for (int p = 0; p < 2; ++p) {
        int r = rr * 2 + p;   // rows 0..15
        int g = node0 + r;
        if (g < n) {
            float a = 0.0f;
#pragma unroll
            for (int k = 0; k < 64; ++k) a += sh[r][k] * sW[k * 32 + f];
            xw2s[(size_t)g * 32 + f] = dis[g] * a;
        }
    }
}

// layer 2 aggregation + bias + relu + head, fused
__global__ __launch_bounds__(ATB) void agg2_head_kernel(
        const float* __restrict__ xw2s, const float* __restrict__ dis,
        const int* __restrict__ sorted, const int* __restrict__ SH,
        const float* __restrict__ b2, const float* __restrict__ Wl,
        const float* __restrict__ bl, float* __restrict__ out,
        int e, int n, int nbuck, int eb) {
    __shared__ float acc[NPB][33];                // 16.9 KB
    int t = threadIdx.x;
    for (int i = t; i < NPB * 33; i += ATB) ((float*)acc)[i] = 0.0f;
    __syncthreads();
    int b = blockIdx.x;
    int start = SH[b * eb];
    int end = (b + 1 < nbuck) ? SH[(b + 1) * eb] : e;
    int sw = t >> 5, f = t & 31;
    for (int j = start + sw; j < end; j += 16) {
        int w = sorted[j];
        int s = w >> 7;
        int dl = w & 127;
        atomicAdd(&acc[dl][f], xw2s[(size_t)s * 32 + f]);   // xw2s pre-scaled by dis[s]
    }
    __syncthreads();
    float wl = Wl[f], bb = b2[f], b0 = bl[0];
    int base = b * NPB;
    for (int nl = sw; nl < NPB; nl += 16) {
        int g = base + nl;
        if (g < n) {
            float v = fmaxf(dis[g] * (acc[nl][f] + xw2s[(size_t)g * 32 + f]) + bb, 0.0f);
            float c = v * wl;
#pragma unroll
            for (int mm = 16; mm >= 1; mm >>= 1) c += __shfl_xor(c, mm, 32);
            if (f == 0) out[g] = c + b0;
        }
    }
}

// ---- host ------------------------------------------------------------------

extern "C" void kernel_launch(void* const* d_in, const int* in_sizes, int n_in,
                              void* d_out, int out_size, void* d_ws, size_t ws_size,
                              hipStream_t stream) {
    const float* x  = (const float*)d_in[0];
    const int*   ei = (const int*)d_in[1];
    const float* W1 = (const float*)d_in[2];
    const float* b1 = (const float*)d_in[3];
    const float* W2 = (const float*)d_in[4];
    const float* b2 = (const float*)d_in[5];
    const float* Wl = (const float*)d_in[6];
    const float* bl = (const float*)d_in[7];
    float* out = (float*)d_out;

    const int n = in_sizes[0] / 26;
    const int e = in_sizes[1] / 2;
    const int* src = ei;
    const int* dst = ei + e;

    const int nbuck = (n + NPB - 1) / NPB;       // 782 for n=100k (<= NBUCK_MAX)
    const int eb    = (e + EPB - 1) / EPB;       // 147 for e=1.2M
    const int m     = nbuck * eb;                // ~115k
    const int msb   = (m + TPB - 1) / TPB;       // 450 (<= 512 for scan_bsum)

    // workspace layout, 256B-aligned
    auto align_up = [](size_t v) { return (v + 255) & ~(size_t)255; };
    char* p = (char*)d_ws;
    int*   H      = (int*)p;    p += align_up((size_t)m * 4);
    int*   SH     = (int*)p;    p += align_up((size_t)m * 4);
    int*   bsum   = (int*)p;    p += align_up(512 * 4);
    int*   sorted = (int*)p;    p += align_up((size_t)e * 4);
    float* dis    = (float*)p;  p += align_up((size_t)n * 4);
    float* sum1   = (float*)p;  p += align_up((size_t)n * 26 * 4);
    float* h1     = (float*)p;  p += align_up((size_t)n * 64 * 4);
    float* xw2s   = (float*)p;  p += align_up((size_t)n * 32 * 4);

    // 1) bucket-sort edges by dst bucket (no global atomics anywhere)
    coarse_hist_kernel<<<eb, TPB, 0, stream>>>(dst, H, e, nbuck, eb);
    scan_block_kernel<<<msb, TPB, 0, stream>>>(H, SH, bsum, m);
    scan_bsum_kernel<<<1, 512, 0, stream>>>(bsum, msb);
    add_offs_kernel<<<msb, TPB, 0, stream>>>(SH, bsum, m);
    bucket_scatter_kernel<<<eb, TPB, 0, stream>>>(src, dst, SH, sorted, e, nbuck, eb);
    bucket_dis_kernel<<<nbuck, NPB, 0, stream>>>(sorted, SH, dis, e, n, nbuck, eb);

    // 2) layer 1: aggregate x (26 feats) per bucket, then transform (+bias+relu)
    agg1_kernel<<<nbuck, ATB, 0, stream>>>(x, dis, sorted, SH, sum1, e, n, nbuck, eb);
    gemm1_kernel<<<(n + 15) / 16, TPB, 0, stream>>>(sum1, dis, W1, b1, h1, n);

    // 3) layer 2: transform (pre-scaled), aggregate + bias + relu + head (fused)
    gemm2_kernel<<<(n + 15) / 16, TPB, 0, stream>>>(h1, dis, W2, xw2s, n);
    agg2_head_kernel<<<nbuck, ATB, 0, stream>>>(xw2s, dis, sorted, SH, b2, Wl, bl, out,
                                                e, n, nbuck, eb);
}

// Round 5
// 180.629 us; speedup vs baseline: 3.2346x; 3.2346x over previous
//
#include <hip/hip_runtime.h>

// GCN 2-layer + linear head on MI355X.
// out = relu(agg(relu(agg(X)@W1 + b1)@W2) + b2) @ Wl + bl
// agg(Y) = D^-1/2 (A+I) D^-1/2 Y  (commutes with the dense transform; layer 1
// aggregates X at 26 feats, layer 2 transforms first at 32 feats).
//
// Build (NO global atomics): coarse per-(bucket,block) LDS hist -> 2-level scan ->
// bucket scatter of packed (src<<7|dstlow) -> per-bucket kernel: LDS degree count,
// LDS scan -> dis/offs, LDS-atomic re-scatter to node-sorted 4B src slots.
// Aggregation: per-node 32-lane gather groups, 4 edges in flight (R3 structure).

#define TPB 256
#define NPB 128              // nodes per bucket (dstlow = 7 bits)
#define EPB 8192             // edges per hist/scatter block
#define NBUCK_MAX 1024

// ---- build -----------------------------------------------------------------

__global__ __launch_bounds__(TPB) void coarse_hist_kernel(
        const int* __restrict__ dst, int* __restrict__ H, int e, int nbuck, int eb) {
    __shared__ int lh[NBUCK_MAX];
    int t = threadIdx.x;
    for (int b = t; b < nbuck; b += TPB) lh[b] = 0;
    __syncthreads();
    int j0 = blockIdx.x * EPB;
    int j1 = min(e, j0 + EPB);
    for (int j = j0 + t; j < j1; j += TPB)
        atomicAdd(&lh[dst[j] >> 7], 1);
    __syncthreads();
    for (int b = t; b < nbuck; b += TPB)
        H[b * eb + blockIdx.x] = lh[b];
}

__global__ __launch_bounds__(TPB) void scan_block_kernel(
        const int* __restrict__ in, int* __restrict__ outx, int* __restrict__ bsum, int m) {
    __shared__ int s[TPB];
    int i = blockIdx.x * TPB + threadIdx.x;
    int v = (i < m) ? in[i] : 0;
    s[threadIdx.x] = v;
    __syncthreads();
#pragma unroll
    for (int d = 1; d < TPB; d <<= 1) {
        int t = (threadIdx.x >= d) ? s[threadIdx.x - d] : 0;
        __syncthreads();
        s[threadIdx.x] += t;
        __syncthreads();
    }
    if (i < m) outx[i] = s[threadIdx.x] - v;  // exclusive
    if (threadIdx.x == TPB - 1) bsum[blockIdx.x] = s[TPB - 1];
}

__global__ __launch_bounds__(512) void scan_bsum_kernel(int* bsum, int nb) {  // nb <= 512
    __shared__ int s[512];
    int i = threadIdx.x;
    int v = (i < nb) ? bsum[i] : 0;
    s[i] = v;
    __syncthreads();
#pragma unroll
    for (int d = 1; d < 512; d <<= 1) {
        int t = (i >= d) ? s[i - d] : 0;
        __syncthreads();
        s[i] += t;
        __syncthreads();
    }
    if (i < nb) bsum[i] = s[i] - v;
}

__global__ __launch_bounds__(TPB) void add_offs_kernel(
        int* __restrict__ SH, const int* __restrict__ bsum, int m) {
    int i = blockIdx.x * TPB + threadIdx.x;
    if (i < m) SH[i] += bsum[i >> 8];
}

__global__ __launch_bounds__(TPB) void bucket_scatter_kernel(
        const int* __restrict__ src, const int* __restrict__ dst,
        const int* __restrict__ SH, int* __restrict__ sortedb, int e, int nbuck, int eb) {
    __shared__ int lc[NBUCK_MAX];
    int t = threadIdx.x;
    for (int b = t; b < nbuck; b += TPB) lc[b] = SH[b * eb + blockIdx.x];
    __syncthreads();
    int j0 = blockIdx.x * EPB;
    int j1 = min(e, j0 + EPB);
    for (int j = j0 + t; j < j1; j += TPB) {
        int d = dst[j];
        int s = src[j];
        int pos = atomicAdd(&lc[d >> 7], 1);   // LDS atomic only
        sortedb[pos] = (s << 7) | (d & 127);
    }
}

// per bucket: degree count -> dis/offs (LDS scan), then node-sorted src slots
__global__ __launch_bounds__(TPB) void bucket_sort_fill_kernel(
        const int* __restrict__ sortedb, const int* __restrict__ SH,
        int* __restrict__ slot, float* __restrict__ dis, int* __restrict__ offs,
        int e, int n, int nbuck, int eb) {
    __shared__ int c[NPB];
    __shared__ int ptr[NPB];
    int b = blockIdx.x, t = threadIdx.x;
    if (t < NPB) c[t] = 0;
    __syncthreads();
    int start = SH[b * eb];
    int end = (b + 1 < nbuck) ? SH[(b + 1) * eb] : e;
    for (int j = start + t; j < end; j += TPB)
        atomicAdd(&c[sortedb[j] & 127], 1);
    __syncthreads();
    int mycnt = (t < NPB) ? c[t] : 0;
    // inclusive Hillis-Steele scan over 128 entries
    for (int d = 1; d < NPB; d <<= 1) {
        int v = 0;
        if (t < NPB && t >= d) v = c[t - d];
        __syncthreads();
        if (t < NPB) c[t] += v;
        __syncthreads();
    }
    if (t < NPB) {
        int excl = c[t] - mycnt;
        ptr[t] = excl;
        int g = b * NPB + t;
        if (g < n) {
            dis[g] = rsqrtf((float)mycnt + 1.0f);
            offs[g] = start + excl;
        }
    }
    if (b == nbuck - 1 && t == 0) offs[n] = e;
    __syncthreads();
    for (int j = start + t; j < end; j += TPB) {
        int w = sortedb[j];
        int pos = atomicAdd(&ptr[w & 127], 1);  // LDS atomic only
        slot[start + pos] = w >> 7;
    }
}

// xs[node][f] = dis[node] * x[node][f]
__global__ __launch_bounds__(TPB) void prescale_kernel(
        const float* __restrict__ x, const float* __restrict__ dis,
        float* __restrict__ xs, int total26) {
    int i = blockIdx.x * TPB + threadIdx.x;
    if (i < total26) {
        int node = i / 26;
        xs[i] = dis[node] * x[i];
    }
}

// ---- layer 1: sum1[g][f] = xs[g][f] + sum_edges xs[s][f]   (F=26) -----------

__global__ __launch_bounds__(TPB) void gather1_kernel(
        const float* __restrict__ xs, const int* __restrict__ offs,
        const int* __restrict__ slot, float* __restrict__ sum1, int n) {
    int sub = threadIdx.x >> 5;
    int f = threadIdx.x & 31;
    int node = blockIdx.x * 8 + sub;
    if (node >= n) return;
    int j = offs[node], end = offs[node + 1];
    float acc = (f < 26) ? xs[(size_t)node * 26 + f] : 0.0f;
    for (; j + 3 < end; j += 4) {
        int s0 = slot[j], s1 = slot[j + 1], s2 = slot[j + 2], s3 = slot[j + 3];
        if (f < 26) {
            float v0 = xs[(size_t)s0 * 26 + f];
            float v1 = xs[(size_t)s1 * 26 + f];
            float v2 = xs[(size_t)s2 * 26 + f];
            float v3 = xs[(size_t)s3 * 26 + f];
            acc += v0 + v1 + v2 + v3;
        }
    }
    for (; j < end; ++j) {
        int s = slot[j];
        if (f < 26) acc += xs[(size_t)s * 26 + f];
    }
    if (f < 26) sum1[(size_t)node * 26 + f] = acc;
}

// h1 = relu(dis[g]*sum1[g] @ W1 + b1),  16 nodes/block
__global__ __launch_bounds__(TPB) void gemm1_kernel(
        const float* __restrict__ sum1, const float* __restrict__ dis,
        const float* __restrict__ W, const float* __restrict__ b1,
        float* __restrict__ h1, int n) {
    __shared__ float sW[26 * 64];
    __shared__ float sx[16][27];
    int t = threadIdx.x;
    for (int i = t; i < 26 * 64; i += TPB) sW[i] = W[i];
    int node0 = blockIdx.x * 16;
    for (int i = t; i < 16 * 26; i += TPB) {
        int r = i / 26, c = i - r * 26;
        int g = node0 + r;
        sx[r][c] = (g < n) ? dis[g] * sum1[(size_t)g * 26 + c] : 0.0f;
    }
    __syncthreads();
    int f = t & 63;
    int rr = t >> 6;  // 0..3
    float bias = b1[f];
#pragma unroll
    for (int p = 0; p < 4; ++p) {
        int r = rr * 4 + p;
        int g = node0 + r;
        if (g < n) {
            float a = bias;
#pragma unroll
            for (int k = 0; k < 26; ++k) a += sx[r][k] * sW[k * 64 + f];
            h1[(size_t)g * 64 + f] = fmaxf(a, 0.0f);
        }
    }
}

// xw2s = dis[g] * (h1[g] @ W2),  16 nodes/block
__global__ __launch_bounds__(TPB) void gemm2_kernel(
        const float* __restrict__ h1, const float* __restrict__ dis,
        const float* __restrict__ W, float* __restrict__ xw2s, int n) {
    __shared__ float sW[64 * 32];
    __shared__ float sh[16][65];
    int t = threadIdx.x;
    for (int i = t; i < 64 * 32; i += TPB) sW[i] = W[i];
    int node0 = blockIdx.x * 16;
    for (int i = t; i < 16 * 64; i += TPB) {
        int r = i >> 6, c = i & 63;
        int g = node0 + r;
        sh[r][c] = (g < n) ? h1[(size_t)g * 64 + c] : 0.0f;
    }
    __syncthreads();
    int f = t & 31;
    int rr = t >> 5;  // 0..7
#pragma unroll
    for (int p = 0; p < 2; ++p) {
        int r = rr * 2 + p;
        int g = node0 + r;
        if (g < n) {
            float a = 0.0f;
#pragma unroll
            for (int k = 0; k < 64; ++k) a += sh[r][k] * sW[k * 32 + f];
            xw2s[(size_t)g * 32 + f] = dis[g] * a;
        }
    }
}

// fused: h2 = relu(dis[g]*(xw2s[g] + sum_edges xw2s[s]) + b2); out = h2 @ Wl + bl
__global__ __launch_bounds__(TPB) void gather2_head_kernel(
        const float* __restrict__ xw2s, const float* __restrict__ dis,
        const int* __restrict__ offs, const int* __restrict__ slot,
        const float* __restrict__ b2, const float* __restrict__ Wl,
        const float* __restrict__ bl, float* __restrict__ out, int n) {
    int sub = threadIdx.x >> 5;
    int f = threadIdx.x & 31;
    int node = blockIdx.x * 8 + sub;
    if (node >= n) return;
    int j = offs[node], end = offs[node + 1];
    float acc = xw2s[(size_t)node * 32 + f];
    for (; j + 3 < end; j += 4) {
        int s0 = slot[j], s1 = slot[j + 1], s2 = slot[j + 2], s3 = slot[j + 3];
        float v0 = xw2s[(size_t)s0 * 32 + f];
        float v1 = xw2s[(size_t)s1 * 32 + f];
        float v2 = xw2s[(size_t)s2 * 32 + f];
        float v3 = xw2s[(size_t)s3 * 32 + f];
        acc += v0 + v1 + v2 + v3;
    }
    for (; j < end; ++j) acc += xw2s[(size_t)slot[j] * 32 + f];
    float v = fmaxf(dis[node] * acc + b2[f], 0.0f);
    float c = v * Wl[f];
#pragma unroll
    for (int mm = 16; mm >= 1; mm >>= 1) c += __shfl_xor(c, mm, 32);
    if (f == 0) out[node] = c + bl[0];
}

// ---- host ------------------------------------------------------------------

extern "C" void kernel_launch(void* const* d_in, const int* in_sizes, int n_in,
                              void* d_out, int out_size, void* d_ws, size_t ws_size,
                              hipStream_t stream) {
    const float* x  = (const float*)d_in[0];
    const int*   ei = (const int*)d_in[1];
    const float* W1 = (const float*)d_in[2];
    const float* b1 = (const float*)d_in[3];
    const float* W2 = (const float*)d_in[4];
    const float* b2 = (const float*)d_in[5];
    const float* Wl = (const float*)d_in[6];
    const float* bl = (const float*)d_in[7];
    float* out = (float*)d_out;

    const int n = in_sizes[0] / 26;
    const int e = in_sizes[1] / 2;
    const int* src = ei;
    const int* dst = ei + e;

    const int nbuck = (n + NPB - 1) / NPB;   // 782 (<= NBUCK_MAX)
    const int eb    = (e + EPB - 1) / EPB;   // 147
    const int m     = nbuck * eb;            // ~115k
    const int msb   = (m + TPB - 1) / TPB;   // 450 (<= 512)

    auto align_up = [](size_t v) { return (v + 255) & ~(size_t)255; };
    char* p = (char*)d_ws;

    // Region A: build tmp {H, SH, bsum, sortedb} (~5.8MB) / sum1 (10.4MB) / xw2s (12.8MB)
    char* A = p;  p += align_up((size_t)n * 32 * 4);
    // Region B: xs (10.4MB) / h1 (25.6MB)
    char* B = p;  p += align_up((size_t)n * 64 * 4);
    int*   slot = (int*)p;    p += align_up((size_t)e * 4);
    float* dis  = (float*)p;  p += align_up((size_t)n * 4);
    int*   offs = (int*)p;    p += align_up((size_t)(n + 1) * 4);

    // build-tmp views inside A
    char* q = A;
    int* H       = (int*)q;   q += align_up((size_t)m * 4);
    int* SH      = (int*)q;   q += align_up((size_t)m * 4);
    int* bsum    = (int*)q;   q += align_up(512 * 4);
    int* sortedb = (int*)q;   q += align_up((size_t)e * 4);

    float* sum1 = (float*)A;
    float* xw2s = (float*)A;
    float* xs   = (float*)B;
    float* h1   = (float*)B;

    // 1) bucket-sorted CSR build (no global atomics anywhere)
    coarse_hist_kernel<<<eb, TPB, 0, stream>>>(dst, H, e, nbuck, eb);
    scan_block_kernel<<<msb, TPB, 0, stream>>>(H, SH, bsum, m);
    scan_bsum_kernel<<<1, 512, 0, stream>>>(bsum, msb);
    add_offs_kernel<<<msb, TPB, 0, stream>>>(SH, bsum, m);
    bucket_scatter_kernel<<<eb, TPB, 0, stream>>>(src, dst, SH, sortedb, e, nbuck, eb);
    bucket_sort_fill_kernel<<<nbuck, TPB, 0, stream>>>(sortedb, SH, slot, dis, offs,
                                                       e, n, nbuck, eb);

    // 2) layer 1: pre-scale, aggregate (26 feats), transform (+bias+relu)
    prescale_kernel<<<((size_t)n * 26 + TPB - 1) / TPB, TPB, 0, stream>>>(x, dis, xs, n * 26);
    gather1_kernel<<<(n + 7) / 8, TPB, 0, stream>>>(xs, offs, slot, sum1, n);
    gemm1_kernel<<<(n + 15) / 16, TPB, 0, stream>>>(sum1, dis, W1, b1, h1, n);

    // 3) layer 2: transform (pre-scaled), aggregate + bias + relu + head (fused)
    gemm2_kernel<<<(n + 15) / 16, TPB, 0, stream>>>(h1, dis, W2, xw2s, n);
    gather2_head_kernel<<<(n + 7) / 8, TPB, 0, stream>>>(xw2s, dis, offs, slot,
                                                         b2, Wl, bl, out, n);
}

// Round 6
// 166.813 us; speedup vs baseline: 3.5025x; 1.0828x over previous
//
#include <hip/hip_runtime.h>

// GCN 2-layer + linear head on MI355X.
// out = relu(agg(relu(agg(X)@W1 + b1)@W2) + b2) @ Wl + bl
// agg(Y) = D^-1/2 (A+I) D^-1/2 Y  (commutes with the dense transform; layer 1
// aggregates X at 26 feats, layer 2 transforms first at 32 feats).
//
// Build (NO global atomics): coarse per-(bucket,block) LDS hist -> 2-level scan ->
// bucket scatter of packed (src<<7|dstlow) -> per-bucket kernel: LDS degree count,
// LDS scan -> dis/offs, LDS-atomic re-scatter to node-sorted 4B src slots, and
// fused prescale xs = dis*x into padded 32-float rows (128B aligned).
// Aggregation: per-node 32-lane gather groups, 8 edges in flight.
// Dense: gemm1+gemm2 fused (h1 lives only in LDS).

#define TPB 256
#define NPB 128              // nodes per bucket (dstlow = 7 bits)
#define EPB 8192             // edges per hist/scatter block
#define NBUCK_MAX 1024

// ---- build -----------------------------------------------------------------

__global__ __launch_bounds__(TPB) void coarse_hist_kernel(
        const int* __restrict__ dst, int* __restrict__ H, int e, int nbuck, int eb) {
    __shared__ int lh[NBUCK_MAX];
    int t = threadIdx.x;
    for (int b = t; b < nbuck; b += TPB) lh[b] = 0;
    __syncthreads();
    int j0 = blockIdx.x * EPB;
    int j1 = min(e, j0 + EPB);
    for (int j = j0 + t; j < j1; j += TPB)
        atomicAdd(&lh[dst[j] >> 7], 1);
    __syncthreads();
    for (int b = t; b < nbuck; b += TPB)
        H[b * eb + blockIdx.x] = lh[b];
}

__global__ __launch_bounds__(TPB) void scan_block_kernel(
        const int* __restrict__ in, int* __restrict__ outx, int* __restrict__ bsum, int m) {
    __shared__ int s[TPB];
    int i = blockIdx.x * TPB + threadIdx.x;
    int v = (i < m) ? in[i] : 0;
    s[threadIdx.x] = v;
    __syncthreads();
#pragma unroll
    for (int d = 1; d < TPB; d <<= 1) {
        int t = (threadIdx.x >= d) ? s[threadIdx.x - d] : 0;
        __syncthreads();
        s[threadIdx.x] += t;
        __syncthreads();
    }
    if (i < m) outx[i] = s[threadIdx.x] - v;  // exclusive
    if (threadIdx.x == TPB - 1) bsum[blockIdx.x] = s[TPB - 1];
}

__global__ __launch_bounds__(512) void scan_bsum_kernel(int* bsum, int nb) {  // nb <= 512
    __shared__ int s[512];
    int i = threadIdx.x;
    int v = (i < nb) ? bsum[i] : 0;
    s[i] = v;
    __syncthreads();
#pragma unroll
    for (int d = 1; d < 512; d <<= 1) {
        int t = (i >= d) ? s[i - d] : 0;
        __syncthreads();
        s[i] += t;
        __syncthreads();
    }
    if (i < nb) bsum[i] = s[i] - v;
}

__global__ __launch_bounds__(TPB) void add_offs_kernel(
        int* __restrict__ SH, const int* __restrict__ bsum, int m) {
    int i = blockIdx.x * TPB + threadIdx.x;
    if (i < m) SH[i] += bsum[i >> 8];
}

__global__ __launch_bounds__(TPB) void bucket_scatter_kernel(
        const int* __restrict__ src, const int* __restrict__ dst,
        const int* __restrict__ SH, int* __restrict__ sortedb, int e, int nbuck, int eb) {
    __shared__ int lc[NBUCK_MAX];
    int t = threadIdx.x;
    for (int b = t; b < nbuck; b += TPB) lc[b] = SH[b * eb + blockIdx.x];
    __syncthreads();
    int j0 = blockIdx.x * EPB;
    int j1 = min(e, j0 + EPB);
    for (int j = j0 + t; j < j1; j += TPB) {
        int d = dst[j];
        int s = src[j];
        int pos = atomicAdd(&lc[d >> 7], 1);   // LDS atomic only
        sortedb[pos] = (s << 7) | (d & 127);
    }
}

// per bucket: degree count -> dis/offs (LDS scan), node-sorted src slots, and
// fused prescale xs[g][0:32] = {dis[g]*x[g][0:26], 0...}  (padded 128B rows)
__global__ __launch_bounds__(TPB) void bucket_sort_fill_kernel(
        const int* __restrict__ sortedb, const int* __restrict__ SH,
        const float* __restrict__ x,
        int* __restrict__ slot, float* __restrict__ dis, int* __restrict__ offs,
        float* __restrict__ xs, int e, int n, int nbuck, int eb) {
    __shared__ int c[NPB];
    __shared__ int ptr[NPB];
    __shared__ float sdis[NPB];
    int b = blockIdx.x, t = threadIdx.x;
    if (t < NPB) c[t] = 0;
    __syncthreads();
    int start = SH[b * eb];
    int end = (b + 1 < nbuck) ? SH[(b + 1) * eb] : e;
    for (int j = start + t; j < end; j += TPB)
        atomicAdd(&c[sortedb[j] & 127], 1);
    __syncthreads();
    int mycnt = (t < NPB) ? c[t] : 0;
    // inclusive Hillis-Steele scan over 128 entries
    for (int d = 1; d < NPB; d <<= 1) {
        int v = 0;
        if (t < NPB && t >= d) v = c[t - d];
        __syncthreads();
        if (t < NPB) c[t] += v;
        __syncthreads();
    }
    if (t < NPB) {
        int excl = c[t] - mycnt;
        ptr[t] = excl;
        float dv = rsqrtf((float)mycnt + 1.0f);
        sdis[t] = dv;
        int g = b * NPB + t;
        if (g < n) {
            dis[g] = dv;
            offs[g] = start + excl;
        }
    }
    if (b == nbuck - 1 && t == 0) offs[n] = e;
    __syncthreads();
    for (int j = start + t; j < end; j += TPB) {
        int w = sortedb[j];
        int pos = atomicAdd(&ptr[w & 127], 1);  // LDS atomic only
        slot[start + pos] = w >> 7;
    }
    // fused prescale (padded rows)
    int base = b * NPB;
    for (int i = t; i < NPB * 32; i += TPB) {
        int r = i >> 5, lane = i & 31;
        int g = base + r;
        if (g < n)
            xs[(size_t)g * 32 + lane] =
                (lane < 26) ? sdis[r] * x[(size_t)g * 26 + lane] : 0.0f;
    }
}

// ---- layer 1 gather: sum1[g][f] = xs[g][f] + sum_edges xs[s][f]  (stride 32) --

__global__ __launch_bounds__(TPB) void gather1_kernel(
        const float* __restrict__ xs, const int* __restrict__ offs,
        const int* __restrict__ slot, float* __restrict__ sum1, int n) {
    int sub = threadIdx.x >> 5;
    int f = threadIdx.x & 31;
    int node = blockIdx.x * 8 + sub;
    if (node >= n) return;
    int j = offs[node], end = offs[node + 1];
    float acc = xs[(size_t)node * 32 + f];
    for (; j + 7 < end; j += 8) {
        int s0 = slot[j], s1 = slot[j + 1], s2 = slot[j + 2], s3 = slot[j + 3];
        int s4 = slot[j + 4], s5 = slot[j + 5], s6 = slot[j + 6], s7 = slot[j + 7];
        float v0 = xs[(size_t)s0 * 32 + f];
        float v1 = xs[(size_t)s1 * 32 + f];
        float v2 = xs[(size_t)s2 * 32 + f];
        float v3 = xs[(size_t)s3 * 32 + f];
        float v4 = xs[(size_t)s4 * 32 + f];
        float v5 = xs[(size_t)s5 * 32 + f];
        float v6 = xs[(size_t)s6 * 32 + f];
        float v7 = xs[(size_t)s7 * 32 + f];
        acc += ((v0 + v1) + (v2 + v3)) + ((v4 + v5) + (v6 + v7));
    }
    for (; j + 3 < end; j += 4) {
        int s0 = slot[j], s1 = slot[j + 1], s2 = slot[j + 2], s3 = slot[j + 3];
        float v0 = xs[(size_t)s0 * 32 + f];
        float v1 = xs[(size_t)s1 * 32 + f];
        float v2 = xs[(size_t)s2 * 32 + f];
        float v3 = xs[(size_t)s3 * 32 + f];
        acc += (v0 + v1) + (v2 + v3);
    }
    for (; j < end; ++j) acc += xs[(size_t)slot[j] * 32 + f];
    sum1[(size_t)node * 32 + f] = acc;   // pad lanes write 0-sums; fully coalesced
}

// ---- fused dense middle: xw2s = dis * (relu(dis*sum1 @ W1 + b1) @ W2) --------

__global__ __launch_bounds__(TPB) void gemm12_kernel(
        const float* __restrict__ sum1, const float* __restrict__ dis,
        const float* __restrict__ W1, const float* __restrict__ b1,
        const float* __restrict__ W2, float* __restrict__ xw2s, int n) {
    __shared__ float sW1[26 * 64];
    __shared__ float sW2[64 * 32];
    __shared__ float sx[16][27];
    __shared__ float sh1[16][65];
    __shared__ float sdis[16];
    int t = threadIdx.x;
    for (int i = t; i < 26 * 64; i += TPB) sW1[i] = W1[i];
    for (int i = t; i < 64 * 32; i += TPB) sW2[i] = W2[i];
    int node0 = blockIdx.x * 16;
    if (t < 16) {
        int g = node0 + t;
        sdis[t] = (g < n) ? dis[g] : 0.0f;
    }
    for (int i = t; i < 16 * 26; i += TPB) {
        int r = i / 26, ccol = i - r * 26;
        int g = node0 + r;
        sx[r][ccol] = (g < n) ? sum1[(size_t)g * 32 + ccol] : 0.0f;
    }
    __syncthreads();
    // phase 1: h1[r][f] = relu(dis[r] * (sx[r] . W1[:,f]) + b1[f]) into LDS
    {
        int f = t & 63;
        int rr = t >> 6;  // 0..3
        float bias = b1[f];
#pragma unroll
        for (int p = 0; p < 4; ++p) {
            int r = rr * 4 + p;
            float a = 0.0f;
#pragma unroll
            for (int k = 0; k < 26; ++k) a += sx[r][k] * sW1[k * 64 + f];
            sh1[r][f] = fmaxf(sdis[r] * a + bias, 0.0f);
        }
    }
    __syncthreads();
    // phase 2: xw2s[g][f2] = dis[r] * (sh1[r] . W2[:,f2])
    {
        int f2 = t & 31;
        int r2 = t >> 5;  // 0..7
#pragma unroll
        for (int p = 0; p < 2; ++p) {
            int r = r2 * 2 + p;
            int g = node0 + r;
            if (g < n) {
                float a = 0.0f;
#pragma unroll
                for (int k = 0; k < 64; ++k) a += sh1[r][k] * sW2[k * 32 + f2];
                xw2s[(size_t)g * 32 + f2] = sdis[r] * a;
            }
        }
    }
}

// ---- layer 2 gather + bias + relu + head, fused ------------------------------

__global__ __launch_bounds__(TPB) void gather2_head_kernel(
        const float* __restrict__ xw2s, const float* __restrict__ dis,
        const int* __restrict__ offs, const int* __restrict__ slot,
        const float* __restrict__ b2, const float* __restrict__ Wl,
        const float* __restrict__ bl, float* __restrict__ out, int n) {
    int sub = threadIdx.x >> 5;
    int f = threadIdx.x & 31;
    int node = blockIdx.x * 8 + sub;
    if (node >= n) return;
    int j = offs[node], end = offs[node + 1];
    float acc = xw2s[(size_t)node * 32 + f];
    for (; j + 7 < end; j += 8) {
        int s0 = slot[j], s1 = slot[j + 1], s2 = slot[j + 2], s3 = slot[j + 3];
        int s4 = slot[j + 4], s5 = slot[j + 5], s6 = slot[j + 6], s7 = slot[j + 7];
        float v0 = xw2s[(size_t)s0 * 32 + f];
        float v1 = xw2s[(size_t)s1 * 32 + f];
        float v2 = xw2s[(size_t)s2 * 32 + f];
        float v3 = xw2s[(size_t)s3 * 32 + f];
        float v4 = xw2s[(size_t)s4 * 32 + f];
        float v5 = xw2s[(size_t)s5 * 32 + f];
        float v6 = xw2s[(size_t)s6 * 32 + f];
        float v7 = xw2s[(size_t)s7 * 32 + f];
        acc += ((v0 + v1) + (v2 + v3)) + ((v4 + v5) + (v6 + v7));
    }
    for (; j + 3 < end; j += 4) {
        int s0 = slot[j], s1 = slot[j + 1], s2 = slot[j + 2], s3 = slot[j + 3];
        float v0 = xw2s[(size_t)s0 * 32 + f];
        float v1 = xw2s[(size_t)s1 * 32 + f];
        float v2 = xw2s[(size_t)s2 * 32 + f];
        float v3 = xw2s[(size_t)s3 * 32 + f];
        acc += (v0 + v1) + (v2 + v3);
    }
    for (; j < end; ++j) acc += xw2s[(size_t)slot[j] * 32 + f];
    float v = fmaxf(dis[node] * acc + b2[f], 0.0f);
    float c = v * Wl[f];
#pragma unroll
    for (int mm = 16; mm >= 1; mm >>= 1) c += __shfl_xor(c, mm, 32);
    if (f == 0) out[node] = c + bl[0];
}

// ---- host ------------------------------------------------------------------

extern "C" void kernel_launch(void* const* d_in, const int* in_sizes, int n_in,
                              void* d_out, int out_size, void* d_ws, size_t ws_size,
                              hipStream_t stream) {
    const float* x  = (const float*)d_in[0];
    const int*   ei = (const int*)d_in[1];
    const float* W1 = (const float*)d_in[2];
    const float* b1 = (const float*)d_in[3];
    const float* W2 = (const float*)d_in[4];
    const float* b2 = (const float*)d_in[5];
    const float* Wl = (const float*)d_in[6];
    const float* bl = (const float*)d_in[7];
    float* out = (float*)d_out;

    const int n = in_sizes[0] / 26;
    const int e = in_sizes[1] / 2;
    const int* src = ei;
    const int* dst = ei + e;

    const int nbuck = (n + NPB - 1) / NPB;   // 782 (<= NBUCK_MAX)
    const int eb    = (e + EPB - 1) / EPB;   // 147
    const int m     = nbuck * eb;            // ~115k
    const int msb   = (m + TPB - 1) / TPB;   // 450 (<= 512)

    auto align_up = [](size_t v) { return (v + 255) & ~(size_t)255; };
    char* p = (char*)d_ws;
    int*   H       = (int*)p;    p += align_up((size_t)m * 4);
    int*   SH      = (int*)p;    p += align_up((size_t)m * 4);
    int*   bsum    = (int*)p;    p += align_up(512 * 4);
    int*   sortedb = (int*)p;    p += align_up((size_t)e * 4);
    int*   slot    = (int*)p;    p += align_up((size_t)e * 4);
    float* dis     = (float*)p;  p += align_up((size_t)n * 4);
    int*   offs    = (int*)p;    p += align_up((size_t)(n + 1) * 4);
    float* xs      = (float*)p;  p += align_up((size_t)n * 32 * 4);
    float* sum1    = (float*)p;  p += align_up((size_t)n * 32 * 4);
    float* xw2s    = (float*)p;  p += align_up((size_t)n * 32 * 4);

    // 1) bucket-sorted CSR build (no global atomics anywhere) + fused prescale
    coarse_hist_kernel<<<eb, TPB, 0, stream>>>(dst, H, e, nbuck, eb);
    scan_block_kernel<<<msb, TPB, 0, stream>>>(H, SH, bsum, m);
    scan_bsum_kernel<<<1, 512, 0, stream>>>(bsum, msb);
    add_offs_kernel<<<msb, TPB, 0, stream>>>(SH, bsum, m);
    bucket_scatter_kernel<<<eb, TPB, 0, stream>>>(src, dst, SH, sortedb, e, nbuck, eb);
    bucket_sort_fill_kernel<<<nbuck, TPB, 0, stream>>>(sortedb, SH, x, slot, dis, offs,
                                                       xs, e, n, nbuck, eb);

    // 2) layer 1 gather (26 feats, padded rows)
    gather1_kernel<<<(n + 7) / 8, TPB, 0, stream>>>(xs, offs, slot, sum1, n);

    // 3) fused dense middle (h1 stays in LDS)
    gemm12_kernel<<<(n + 15) / 16, TPB, 0, stream>>>(sum1, dis, W1, b1, W2, xw2s, n);

    // 4) layer 2 gather + bias + relu + head (fused)
    gather2_head_kernel<<<(n + 7) / 8, TPB, 0, stream>>>(xw2s, dis, offs, slot,
                                                         b2, Wl, bl, out, n);
}